// Round 2
// baseline (103072.229 us; speedup 1.0000x reference)
//
#include <hip/hip_runtime.h>
#include <cstdint>
#include <cstddef>
#include <math.h>

// Exact Viterbi decode: N=512 states, T=8192, M=50257 tokens.
// Forward recurrence computed bit-exactly by ONE 512-thread workgroup
// (8 waves; thread j owns column j; v_j lives in a REGISTER only).
// Exactness-preserving pruning (same proof as before, twice HW-verified):
//   SV  = union over waves of {i : v_i >= wavemax - DELTA_W}   (heuristic set)
//   T   = min_j (achieved column max over SV)                  (achieved bound)
//   rows with fl(v_i + R) < T (R = global max row-max; IEEE add monotone)
//   cannot win or tie any column; extras {fl(v+R) >= T} \ SV handled exactly
//   on a rare path. All merges use (value strict >, then smaller index) =>
//   exact first-index argmax, order-independent (padding dups idempotent).
//
// R1 change: survivor scan via LDS STAGING with global_load_lds (fire-and-
// forget, no dest VGPRs => compiler cannot re-serialize the gathers; one
// vmcnt drain per batch instead of ~70 serialized L2 round-trips/step).

#define NT 512
#define TT 8192
#define MT 50257
#define DELTA_W 0.15f
#define NEG_INF (-3.402823466e38f)

#define SB 64                    // staged survivor rows per batch (128 KiB LDS)

#define BT_L 32                  // backtrace segment length
#define BT_S (TT / BT_L)         // 256 segments

// ---- workspace layout (bytes) ----
#define WS_LOGPI   0u            // 512 f32
#define WS_VLAST   2048u         // 512 f32
#define WS_BOUND   4096u         // 257 i32
#define WS_ROWMAX  5632u         // 512 f32
#define WS_MAPS    8192u         // 256*512 u16 = 262144
#define WS_LA      270336u       // 512*512 f32 = 1048576 (row-major logA)
#define WS_EMIS    1318912u      // 8192*512 f32 = 16777216
#define WS_BP      18096128u     // 8192*512 u16 = 8388608
#define WS_NEED    26484736u

// Correctly-rounded fp32 logs via fp64 (verified: absmax 0 vs numpy ref).
__global__ void prep_logs(const float* __restrict__ A, const float* __restrict__ Pi,
                          float* __restrict__ lA, float* __restrict__ logPi) {
    int idx = blockIdx.x * blockDim.x + threadIdx.x;
    if (idx < NT * NT) {
        lA[idx] = (float)log((double)A[idx]);
    } else if (idx < NT * NT + NT) {
        int j = idx - NT * NT;
        logPi[j] = (float)log((double)Pi[j]);
    }
}

__global__ void prep_rowmax(const float* __restrict__ lA, float* __restrict__ rowmax) {
    __shared__ float s[4];
    int i = blockIdx.x;
    int t = threadIdx.x;                    // 256 threads
    float m = fmaxf(lA[i * NT + t], lA[i * NT + t + 256]);
    for (int k = 32; k >= 1; k >>= 1) m = fmaxf(m, __shfl_xor(m, k, 64));
    if ((t & 63) == 0) s[t >> 6] = m;
    __syncthreads();
    if (t == 0) {
        float r = fmaxf(fmaxf(s[0], s[1]), fmaxf(s[2], s[3]));
        rowmax[i] = r;
    }
}

__global__ void prep_emis(const float* __restrict__ B, const int* __restrict__ tok,
                          float* __restrict__ emis) {
    int idx = blockIdx.x * blockDim.x + threadIdx.x;   // t*512 + j
    if (idx >= TT * NT) return;
    int t = idx >> 9;
    int j = idx & (NT - 1);
    int tk = tok[t];
    float e;
    if (tk < 0) e = (float)log((double)(1.0f / 512.0f));
    else        e = (float)log((double)B[(size_t)j * MT + tk]);
    emis[idx] = e;
}

// async global->LDS, 16 B per lane (per-lane gptr, wave-uniform lptr, lane*16 dest)
__device__ __forceinline__ void glds16(const float* g, float* l) {
    __builtin_amdgcn_global_load_lds(
        (const __attribute__((address_space(1))) void*)g,
        (__attribute__((address_space(3))) void*)l, 16, 0, 0);
}

// 512 threads / 8 waves. 4 barriers per step (common path, n <= 64 -> 1 batch... 2 if n>64).
__launch_bounds__(NT, 1)
__global__ void viterbi_fwd_exact(const float* __restrict__ lA,
                                  const float* __restrict__ rowmax,
                                  const float* __restrict__ emis,
                                  const float* __restrict__ logPi,
                                  unsigned short* __restrict__ bp,
                                  float* __restrict__ vlast) {
    __shared__ float2 SV[2][560];            // double-buffered survivors (v, idx bits)
    __shared__ float2 SVX[560];              // extras (rare)
    __shared__ alignas(16) float redR[8];    // rowmax partials
    __shared__ alignas(16) float redT[8];    // T partials
    __shared__ int nCtr[2];
    __shared__ int nCtrX;
    __shared__ alignas(16) float stage[SB * NT];   // 128 KiB staged lA rows

    const int tid  = threadIdx.x;
    const int j    = tid;                    // column AND row owned
    const int lane = tid & 63;
    const int wave = tid >> 6;               // 0..7
    const unsigned long long below = (1ull << lane) - 1ull;
    const float* __restrict__ lAj = lA + j;

    // ---- preamble: warm lA into L2; R; counters; v0 ----
    float acc = 0.0f;
    {
        const float4* lAf4 = (const float4*)lA;
        for (int k = tid; k < (NT * NT) / 4; k += NT) acc += lAf4[k].x;
    }
    float r = rowmax[j];
    #pragma unroll
    for (int d = 1; d <= 32; d <<= 1) r = fmaxf(r, __shfl_xor(r, d, 64));
    if (lane == 0) redR[wave] = r;
    if (tid == 0) { nCtr[0] = 0; nCtr[1] = 0; nCtrX = 0; }
    __syncthreads();
    float4 rr0 = *(const float4*)redR;
    float4 rr1 = *(const float4*)(redR + 4);
    const float R = fmaxf(fmaxf(fmaxf(rr0.x, rr0.y), fmaxf(rr0.z, rr0.w)),
                          fmaxf(fmaxf(rr1.x, rr1.y), fmaxf(rr1.z, rr1.w)));
    if (acc == 1.2345e30f && j == 511) SVX[0].x = acc;   // keep warm loads alive

    float v = logPi[j] + emis[j];            // exact v0 (single-rounded == ref)

    for (int t = 1; t < TT; ++t) {
        const int p = t & 1;
        // ---- PH1: emis issue; per-wave select; compact ----
        float e = emis[(size_t)t * NT + j];  // consumed at finalize
        float wm = v;
        #pragma unroll
        for (int d = 1; d <= 32; d <<= 1) wm = fmaxf(wm, __shfl_xor(wm, d, 64));
        bool pred = (v >= wm - DELTA_W);
        unsigned long long mk = __ballot(pred);
        int base = 0;
        if (lane == 0) base = atomicAdd(&nCtr[p], __popcll(mk));
        base = __shfl(base, 0, 64);
        if (pred) SV[p][base + __popcll(mk & below)] = make_float2(v, __int_as_float(j));
        __syncthreads();                     // B1: survivors final

        // ---- PH2a: staged scan of survivors ----
        const int n   = nCtr[p];             // >= 8 (each wave's max row selected)
        const int nm1 = n - 1;
        float mval = NEG_INF;
        int   bidx = 0x7fffffff;
        for (int s0 = 0; s0 < n; s0 += SB) {
            int bcnt = n - s0; if (bcnt > SB) bcnt = SB;
            const int bpad = (bcnt + 7) & ~7;          // multiple of 8, <= SB
            // stage bpad rows: wave w owns slots w, 8+w, ... (2KB each, 2 glds)
            #pragma unroll
            for (int u = 0; u < 8; ++u) {
                const int q = u * 8 + wave;            // wave-uniform
                if (q < bpad) {
                    int gs = s0 + q; if (gs > nm1) gs = nm1;   // dup-pad (idempotent)
                    const int idx = __float_as_int(SV[p][gs].y);
                    const float* gA = lA + (((unsigned)idx) << 9) + (lane << 2);
                    float* lb = &stage[q * NT];
                    glds16(gA, lb);                    // cols [0,256)
                    glds16(gA + 256, lb + 256);        // cols [256,512)
                }
            }
            __syncthreads();                 // B1.5: stage visible (drains vmcnt)
            #pragma unroll 4
            for (int s = 0; s < bpad; ++s) {
                int gs = s0 + s; if (gs > nm1) gs = nm1;
                const float2 sv = SV[p][gs];           // LDS broadcast
                const float aij = stage[s * NT + j];   // conflict-free (2 lanes/bank)
                const float sc = sv.x + aij;           // single-rounded add == ref
                const int   is = __float_as_int(sv.y);
                if (sc > mval || (sc == mval && is < bidx)) { mval = sc; bidx = is; }
            }
            if (s0 + SB < n) __syncthreads();          // buffer reuse (rare: n > 64)
        }
        float tmin = mval;
        #pragma unroll
        for (int d = 1; d <= 32; d <<= 1) tmin = fminf(tmin, __shfl_xor(tmin, d, 64));
        if (lane == 0) redT[wave] = tmin;
        if (tid == 0) { nCtr[p ^ 1] = 0; nCtrX = 0; }   // safe: old reads pre-B1
        __syncthreads();                     // B2

        // ---- PH2b: T; extras compact (rare) ----
        float4 t0 = *(const float4*)redT;
        float4 t1 = *(const float4*)(redT + 4);
        float T = fminf(fminf(fminf(t0.x, t0.y), fminf(t0.z, t0.w)),
                        fminf(fminf(t1.x, t1.y), fminf(t1.z, t1.w)));
        bool px = (v + R >= T) && !pred;     // fl(v+R) monotone upper bound
        unsigned long long mkx = __ballot(px);
        if (mkx != 0ull) {                   // ~never
            int bx = 0;
            if (lane == 0) bx = atomicAdd(&nCtrX, __popcll(mkx));
            bx = __shfl(bx, 0, 64);
            if (px) SVX[bx + __popcll(mkx & below)] = make_float2(v, __int_as_float(j));
        }
        __syncthreads();                     // B3

        // ---- PH2c: rare extras scan (serial gather; ~never taken); finalize ----
        const int nX = nCtrX;                // block-uniform
        if (nX > 0) {
            for (int s0 = 0; s0 < nX; s0 += 16) {
                float2 q[16];
                #pragma unroll
                for (int k = 0; k < 16; ++k) {
                    int s = s0 + k;
                    q[k] = SVX[s < nX ? s : nX - 1];
                }
                float a[16];
                #pragma unroll
                for (int k = 0; k < 16; ++k)
                    a[k] = lAj[(size_t)__float_as_int(q[k].y) * NT];
                #pragma unroll
                for (int k = 0; k < 16; ++k) {
                    float sc = q[k].x + a[k];
                    int   is = __float_as_int(q[k].y);
                    if (sc > mval || (sc == mval && is < bidx)) { mval = sc; bidx = is; }
                }
            }
        }
        float vn = mval + e;                 // single-rounded == ref
        bp[(size_t)t * NT + j] = (unsigned short)bidx;
        if (t == TT - 1) vlast[j] = vn;
        v = vn;
    }
}

// ---- backtrace: per-segment map composition (verified exact) ----
__launch_bounds__(NT, 1)
__global__ void bt_maps(const unsigned short* __restrict__ bp,
                        unsigned short* __restrict__ maps) {
    __shared__ unsigned short bps[BT_L * NT];
    const int s = blockIdx.x;
    const int tlo = BT_L * s + 1;
    int thi = BT_L * (s + 1); if (thi > TT - 1) thi = TT - 1;
    const int nt = thi - tlo + 1;
    for (int k = threadIdx.x; k < nt * NT; k += NT)
        bps[k] = bp[(size_t)tlo * NT + k];
    __syncthreads();
    int cur = threadIdx.x;
    for (int r = nt - 1; r >= 0; --r) cur = bps[r * NT + cur];
    maps[s * NT + threadIdx.x] = (unsigned short)cur;
}

__launch_bounds__(NT, 1)
__global__ void bt_bound(const float* __restrict__ vlast,
                         const unsigned short* __restrict__ maps,
                         int* __restrict__ bound) {
    __shared__ float sv[NT];
    __shared__ int   si[NT];
    int j = threadIdx.x;
    sv[j] = vlast[j]; si[j] = j;
    __syncthreads();
    for (int off = NT / 2; off > 0; off >>= 1) {
        if (j < off) {
            float v2 = sv[j + off]; int i2 = si[j + off];
            if (v2 > sv[j] || (v2 == sv[j] && i2 < si[j])) { sv[j] = v2; si[j] = i2; }
        }
        __syncthreads();
    }
    if (j == 0) {
        int cur = si[0];
        bound[BT_S] = cur;
        for (int s = BT_S - 1; s >= 0; --s) {
            cur = maps[s * NT + cur];
            bound[s] = cur;
        }
    }
}

__launch_bounds__(NT, 1)
__global__ void bt_path(const unsigned short* __restrict__ bp,
                        const int* __restrict__ bound,
                        int* __restrict__ path) {
    __shared__ unsigned short bps[BT_L * NT];
    const int s = blockIdx.x;
    const int tlo = BT_L * s + 1;
    int thi = BT_L * (s + 1); if (thi > TT - 1) thi = TT - 1;
    const int nt = thi - tlo + 1;
    for (int k = threadIdx.x; k < nt * NT; k += NT)
        bps[k] = bp[(size_t)tlo * NT + k];
    __syncthreads();
    if (threadIdx.x == 0) {
        int cur = bound[s + 1];
        if (s == BT_S - 1) path[TT - 1] = cur;
        for (int r = nt - 1; r >= 0; --r) {
            cur = bps[r * NT + cur];
            path[tlo - 1 + r] = cur;
        }
    }
}

extern "C" void kernel_launch(void* const* d_in, const int* in_sizes, int n_in,
                              void* d_out, int out_size, void* d_ws, size_t ws_size,
                              hipStream_t stream) {
    const int*   tok = (const int*)d_in[0];
    const float* A   = (const float*)d_in[1];
    const float* B   = (const float*)d_in[2];
    const float* Pi  = (const float*)d_in[3];
    int* path = (int*)d_out;
    char* ws = (char*)d_ws;
    if (ws_size < (size_t)WS_NEED) return;

    float* logPi          = (float*)(ws + WS_LOGPI);
    float* vlast          = (float*)(ws + WS_VLAST);
    int*   bound          = (int*)(ws + WS_BOUND);
    float* rowmax         = (float*)(ws + WS_ROWMAX);
    unsigned short* maps  = (unsigned short*)(ws + WS_MAPS);
    float* lA             = (float*)(ws + WS_LA);
    float* emis           = (float*)(ws + WS_EMIS);
    unsigned short* bpp   = (unsigned short*)(ws + WS_BP);

    prep_logs  <<<(NT * NT + NT + 255) / 256, 256, 0, stream>>>(A, Pi, lA, logPi);
    prep_emis  <<<(TT * NT) / 256,            256, 0, stream>>>(B, tok, emis);
    prep_rowmax<<<NT, 256, 0, stream>>>(lA, rowmax);
    viterbi_fwd_exact<<<1, NT, 0, stream>>>(lA, rowmax, emis, logPi, bpp, vlast);
    bt_maps  <<<BT_S, NT, 0, stream>>>(bpp, maps);
    bt_bound <<<1,    NT, 0, stream>>>(vlast, maps, bound);
    bt_path  <<<BT_S, NT, 0, stream>>>(bpp, bound, path);
}

// Round 3
// 93903.363 us; speedup vs baseline: 1.0976x; 1.0976x over previous
//
#include <hip/hip_runtime.h>
#include <cstdint>
#include <cstddef>
#include <math.h>

// Exact Viterbi decode: N=512 states, T=8192, M=50257 tokens.
// Forward recurrence computed bit-exactly by block 0 (512 threads, 8 waves;
// thread j owns column j; v_j lives in a REGISTER only).
// Exactness-preserving pruning (twice HW-verified):
//   SV  = union over waves of {i : v_i >= wavemax - DELTA_W}   (heuristic set)
//   T   = min_j (achieved column max over SV)                  (achieved bound)
//   rows with fl(v_i + R) < T (R = global max row-max; IEEE add monotone)
//   cannot win or tie any column; extras {fl(v+R) >= T} \ SV handled exactly
//   on a rare path. All merges use (value strict >, then smaller index) =>
//   exact first-index argmax, order-independent.
//
// R2 change: DVFS heater. 1-CU kernels idle the SMU governor (evidence:
// 40% run-to-run variance, later dispatches slower, VALUBusy consistent
// with ~600 MHz shader clock). Blocks 1..191 spin dependent-FMA on other
// CUs until block 0 sets a device-scope flag => sustained high clock.
// Scan structure reverted to the verified R0 batched-gather (R1's LDS
// staging regressed 10%: serialized vmcnt drain + 128KB/step LDS writes).

#define NT 512
#define TT 8192
#define MT 50257
#define DELTA_W 0.15f
#define NEG_INF (-3.402823466e38f)

#define GRID_FW 192              // block 0 = real work; 191 heater blocks

#define BT_L 32                  // backtrace segment length
#define BT_S (TT / BT_L)         // 256 segments

// ---- workspace layout (bytes) ----
#define WS_LOGPI   0u            // 512 f32
#define WS_VLAST   2048u         // 512 f32
#define WS_BOUND   4096u         // 257 i32
#define WS_FLAG    5248u         // 1 i32 (done flag, zeroed by prep_logs)
#define WS_ROWMAX  5632u         // 512 f32
#define WS_MAPS    8192u         // 256*512 u16 = 262144
#define WS_LA      270336u       // 512*512 f32 = 1048576 (row-major logA)
#define WS_EMIS    1318912u      // 8192*512 f32 = 16777216
#define WS_BP      18096128u     // 8192*512 u16 = 8388608
#define WS_NEED    26484736u

// Correctly-rounded fp32 logs via fp64 (verified: absmax 0 vs numpy ref).
__global__ void prep_logs(const float* __restrict__ A, const float* __restrict__ Pi,
                          float* __restrict__ lA, float* __restrict__ logPi,
                          int* __restrict__ done) {
    int idx = blockIdx.x * blockDim.x + threadIdx.x;
    if (idx < NT * NT) {
        lA[idx] = (float)log((double)A[idx]);
    } else if (idx < NT * NT + NT) {
        int j = idx - NT * NT;
        logPi[j] = (float)log((double)Pi[j]);
    } else if (idx == NT * NT + NT) {
        *done = 0;
    }
}

__global__ void prep_rowmax(const float* __restrict__ lA, float* __restrict__ rowmax) {
    __shared__ float s[4];
    int i = blockIdx.x;
    int t = threadIdx.x;                    // 256 threads
    float m = fmaxf(lA[i * NT + t], lA[i * NT + t + 256]);
    for (int k = 32; k >= 1; k >>= 1) m = fmaxf(m, __shfl_xor(m, k, 64));
    if ((t & 63) == 0) s[t >> 6] = m;
    __syncthreads();
    if (t == 0) {
        float r = fmaxf(fmaxf(s[0], s[1]), fmaxf(s[2], s[3]));
        rowmax[i] = r;
    }
}

__global__ void prep_emis(const float* __restrict__ B, const int* __restrict__ tok,
                          float* __restrict__ emis) {
    int idx = blockIdx.x * blockDim.x + threadIdx.x;   // t*512 + j
    if (idx >= TT * NT) return;
    int t = idx >> 9;
    int j = idx & (NT - 1);
    int tk = tok[t];
    float e;
    if (tk < 0) e = (float)log((double)(1.0f / 512.0f));
    else        e = (float)log((double)B[(size_t)j * MT + tk]);
    emis[idx] = e;
}

// 512 threads / 8 waves in block 0; blocks 1.. are DVFS heaters.
__launch_bounds__(NT, 1)
__global__ void viterbi_fwd_exact(const float* __restrict__ lA,
                                  const float* __restrict__ rowmax,
                                  const float* __restrict__ emis,
                                  const float* __restrict__ logPi,
                                  unsigned short* __restrict__ bp,
                                  float* __restrict__ vlast,
                                  int* __restrict__ done) {
    if (blockIdx.x != 0) {
        // ---- heater: dependent FMA chain; poll done flag every ~2us ----
        __shared__ volatile int stop;
        if (threadIdx.x == 0) stop = 0;
        __syncthreads();
        float x = 1.0f + (float)threadIdx.x * 1e-6f;
        for (int it = 0; it < 2000000; ++it) {
            #pragma unroll
            for (int k = 0; k < 512; ++k)
                x = __builtin_fmaf(x, 0.99999988f, 1e-7f);
            if (threadIdx.x == 0 &&
                __hip_atomic_load(done, __ATOMIC_RELAXED, __HIP_MEMORY_SCOPE_AGENT))
                stop = 1;
            if (stop) break;
        }
        asm volatile("" :: "v"(x));          // keep chain alive
        return;
    }

    __shared__ float2 SV[2][560];            // double-buffered survivors (v, idx bits)
    __shared__ float2 SVX[560];              // extras (rare)
    __shared__ alignas(16) float redR[8];    // rowmax partials
    __shared__ alignas(16) float redT[8];    // T partials
    __shared__ int nCtr[2];
    __shared__ int nCtrX;

    const int tid  = threadIdx.x;
    const int j    = tid;                    // column AND row owned
    const int lane = tid & 63;
    const int wave = tid >> 6;               // 0..7
    const unsigned long long below = (1ull << lane) - 1ull;
    const float* __restrict__ lAj = lA + j;

    // ---- preamble: warm lA into local L1/L2; R; counters; v0 ----
    float acc = 0.0f;
    {
        const float4* lAf4 = (const float4*)lA;
        for (int k = tid; k < (NT * NT) / 4; k += NT) acc += lAf4[k].x;
    }
    float r = rowmax[j];
    #pragma unroll
    for (int d = 1; d <= 32; d <<= 1) r = fmaxf(r, __shfl_xor(r, d, 64));
    if (lane == 0) redR[wave] = r;
    if (tid == 0) { nCtr[0] = 0; nCtr[1] = 0; nCtrX = 0; }
    __syncthreads();
    float4 rr0 = *(const float4*)redR;
    float4 rr1 = *(const float4*)(redR + 4);
    const float R = fmaxf(fmaxf(fmaxf(rr0.x, rr0.y), fmaxf(rr0.z, rr0.w)),
                          fmaxf(fmaxf(rr1.x, rr1.y), fmaxf(rr1.z, rr1.w)));
    if (acc == 1.2345e30f && j == 511) SVX[0].x = acc;   // keep warm loads alive

    float v = logPi[j] + emis[j];            // exact v0 (single-rounded == ref)

    for (int t = 1; t < TT; ++t) {
        const int p = t & 1;
        // ---- PH1: emis issue; per-wave select; compact ----
        float e = emis[(size_t)t * NT + j];  // consumed at finalize
        float wm = v;
        #pragma unroll
        for (int d = 1; d <= 32; d <<= 1) wm = fmaxf(wm, __shfl_xor(wm, d, 64));
        bool pred = (v >= wm - DELTA_W);
        unsigned long long mk = __ballot(pred);
        int base = 0;
        if (lane == 0) base = atomicAdd(&nCtr[p], __popcll(mk));
        base = __shfl(base, 0, 64);
        if (pred) SV[p][base + __popcll(mk & below)] = make_float2(v, __int_as_float(j));
        __syncthreads();                     // B1

        // ---- PH2a: scan survivors (chunks of 16); T partials; resets ----
        const int n = nCtr[p];               // >= 8 (each wave's max row selected)
        float mval = NEG_INF;
        int   bidx = 0x7fffffff;
        for (int s0 = 0; s0 < n; s0 += 16) {
            float2 q[16];
            #pragma unroll
            for (int k = 0; k < 16; ++k) {
                int s = s0 + k;
                q[k] = SV[p][s < n ? s : n - 1];    // clamp: dup merge is idempotent
            }
            float a[16];
            #pragma unroll
            for (int k = 0; k < 16; ++k)
                a[k] = lAj[(size_t)__float_as_int(q[k].y) * NT];
            #pragma unroll
            for (int k = 0; k < 16; ++k) {
                float sc = q[k].x + a[k];           // single-rounded add == ref
                int   is = __float_as_int(q[k].y);
                if (sc > mval || (sc == mval && is < bidx)) { mval = sc; bidx = is; }
            }
        }
        float tmin = mval;
        #pragma unroll
        for (int d = 1; d <= 32; d <<= 1) tmin = fminf(tmin, __shfl_xor(tmin, d, 64));
        if (lane == 0) redT[wave] = tmin;
        if (tid == 0) { nCtr[p ^ 1] = 0; nCtrX = 0; }   // safe: old reads pre-B1
        __syncthreads();                     // B2

        // ---- PH2b: T; extras compact (rare) ----
        float4 t0 = *(const float4*)redT;
        float4 t1 = *(const float4*)(redT + 4);
        float T = fminf(fminf(fminf(t0.x, t0.y), fminf(t0.z, t0.w)),
                        fminf(fminf(t1.x, t1.y), fminf(t1.z, t1.w)));
        bool px = (v + R >= T) && !pred;     // fl(v+R) monotone upper bound
        unsigned long long mkx = __ballot(px);
        if (mkx != 0ull) {                   // ~never
            int bx = 0;
            if (lane == 0) bx = atomicAdd(&nCtrX, __popcll(mkx));
            bx = __shfl(bx, 0, 64);
            if (px) SVX[bx + __popcll(mkx & below)] = make_float2(v, __int_as_float(j));
        }
        __syncthreads();                     // B3

        // ---- PH2c: rare extras scan; finalize ----
        const int nX = nCtrX;                // block-uniform
        if (nX > 0) {
            for (int s0 = 0; s0 < nX; s0 += 16) {
                float2 q[16];
                #pragma unroll
                for (int k = 0; k < 16; ++k) {
                    int s = s0 + k;
                    q[k] = SVX[s < nX ? s : nX - 1];
                }
                float a[16];
                #pragma unroll
                for (int k = 0; k < 16; ++k)
                    a[k] = lAj[(size_t)__float_as_int(q[k].y) * NT];
                #pragma unroll
                for (int k = 0; k < 16; ++k) {
                    float sc = q[k].x + a[k];
                    int   is = __float_as_int(q[k].y);
                    if (sc > mval || (sc == mval && is < bidx)) { mval = sc; bidx = is; }
                }
            }
        }
        float vn = mval + e;                 // single-rounded == ref
        bp[(size_t)t * NT + j] = (unsigned short)bidx;
        if (t == TT - 1) vlast[j] = vn;
        v = vn;
    }

    // ---- release heaters ----
    if (tid == 0)
        __hip_atomic_store(done, 1, __ATOMIC_RELAXED, __HIP_MEMORY_SCOPE_AGENT);
}

// ---- backtrace: per-segment map composition (verified exact) ----
__launch_bounds__(NT, 1)
__global__ void bt_maps(const unsigned short* __restrict__ bp,
                        unsigned short* __restrict__ maps) {
    __shared__ unsigned short bps[BT_L * NT];
    const int s = blockIdx.x;
    const int tlo = BT_L * s + 1;
    int thi = BT_L * (s + 1); if (thi > TT - 1) thi = TT - 1;
    const int nt = thi - tlo + 1;
    for (int k = threadIdx.x; k < nt * NT; k += NT)
        bps[k] = bp[(size_t)tlo * NT + k];
    __syncthreads();
    int cur = threadIdx.x;
    for (int r = nt - 1; r >= 0; --r) cur = bps[r * NT + cur];
    maps[s * NT + threadIdx.x] = (unsigned short)cur;
}

__launch_bounds__(NT, 1)
__global__ void bt_bound(const float* __restrict__ vlast,
                         const unsigned short* __restrict__ maps,
                         int* __restrict__ bound) {
    __shared__ float sv[NT];
    __shared__ int   si[NT];
    int j = threadIdx.x;
    sv[j] = vlast[j]; si[j] = j;
    __syncthreads();
    for (int off = NT / 2; off > 0; off >>= 1) {
        if (j < off) {
            float v2 = sv[j + off]; int i2 = si[j + off];
            if (v2 > sv[j] || (v2 == sv[j] && i2 < si[j])) { sv[j] = v2; si[j] = i2; }
        }
        __syncthreads();
    }
    if (j == 0) {
        int cur = si[0];
        bound[BT_S] = cur;
        for (int s = BT_S - 1; s >= 0; --s) {
            cur = maps[s * NT + cur];
            bound[s] = cur;
        }
    }
}

__launch_bounds__(NT, 1)
__global__ void bt_path(const unsigned short* __restrict__ bp,
                        const int* __restrict__ bound,
                        int* __restrict__ path) {
    __shared__ unsigned short bps[BT_L * NT];
    const int s = blockIdx.x;
    const int tlo = BT_L * s + 1;
    int thi = BT_L * (s + 1); if (thi > TT - 1) thi = TT - 1;
    const int nt = thi - tlo + 1;
    for (int k = threadIdx.x; k < nt * NT; k += NT)
        bps[k] = bp[(size_t)tlo * NT + k];
    __syncthreads();
    if (threadIdx.x == 0) {
        int cur = bound[s + 1];
        if (s == BT_S - 1) path[TT - 1] = cur;
        for (int r = nt - 1; r >= 0; --r) {
            cur = bps[r * NT + cur];
            path[tlo - 1 + r] = cur;
        }
    }
}

extern "C" void kernel_launch(void* const* d_in, const int* in_sizes, int n_in,
                              void* d_out, int out_size, void* d_ws, size_t ws_size,
                              hipStream_t stream) {
    const int*   tok = (const int*)d_in[0];
    const float* A   = (const float*)d_in[1];
    const float* B   = (const float*)d_in[2];
    const float* Pi  = (const float*)d_in[3];
    int* path = (int*)d_out;
    char* ws = (char*)d_ws;
    if (ws_size < (size_t)WS_NEED) return;

    float* logPi          = (float*)(ws + WS_LOGPI);
    float* vlast          = (float*)(ws + WS_VLAST);
    int*   bound          = (int*)(ws + WS_BOUND);
    int*   done           = (int*)(ws + WS_FLAG);
    float* rowmax         = (float*)(ws + WS_ROWMAX);
    unsigned short* maps  = (unsigned short*)(ws + WS_MAPS);
    float* lA             = (float*)(ws + WS_LA);
    float* emis           = (float*)(ws + WS_EMIS);
    unsigned short* bpp   = (unsigned short*)(ws + WS_BP);

    prep_logs  <<<(NT * NT + NT + 256) / 256, 256, 0, stream>>>(A, Pi, lA, logPi, done);
    prep_emis  <<<(TT * NT) / 256,            256, 0, stream>>>(B, tok, emis);
    prep_rowmax<<<NT, 256, 0, stream>>>(lA, rowmax);
    viterbi_fwd_exact<<<GRID_FW, NT, 0, stream>>>(lA, rowmax, emis, logPi, bpp, vlast, done);
    bt_maps  <<<BT_S, NT, 0, stream>>>(bpp, maps);
    bt_bound <<<1,    NT, 0, stream>>>(vlast, maps, bound);
    bt_path  <<<BT_S, NT, 0, stream>>>(bpp, bound, path);
}

// Round 4
// 68866.022 us; speedup vs baseline: 1.4967x; 1.3636x over previous
//
#include <hip/hip_runtime.h>
#include <cstdint>
#include <cstddef>
#include <math.h>

// Exact Viterbi decode: N=512 states, T=8192, M=50257 tokens.
// Forward recurrence computed bit-exactly by ONE 512-thread workgroup
// (8 waves; thread j owns column j; v_j lives in a REGISTER only).
// Exactness-preserving pruning (twice HW-verified):
//   SV  = union over waves of {i : v_i >= wavemax - DELTA_W}   (heuristic set)
//   T   = min_j (achieved column max over SV)                  (achieved bound)
//   rows with fl(v_i + R) < T (R = global max row-max; IEEE add monotone)
//   cannot win or tie any column; extras {fl(v+R) >= T} \ SV handled exactly
//   on a rare path.
//
// R4 change (theory: scan was L1-miss-latency bound — thousands of 4B
// column gathers/step at ~200-700cy with few outstanding; emis/bp streams
// evicted lA from L2):
//  (a) ROW-PARALLEL scan: each wave reads whole survivor rows of lA
//      contiguously (2x float4 per lane) and merges into per-column packed
//      keys via LDS atomicMax(u64). key = orderable(sc)<<32 | (511-i):
//      exact max + first-index tie-break, order-independent => bit-exact
//      same result as the sequential compare chain.
//  (b) emis loads / bp stores non-temporal => lA stays L2-resident.
//  (c) heaters removed (R3 proved clock is not the issue).

#define NT 512
#define TT 8192
#define MT 50257
#define DELTA_W 0.15f
#define NEG_INF (-3.402823466e38f)

#define BT_L 32                  // backtrace segment length
#define BT_S (TT / BT_L)         // 256 segments

// ---- workspace layout (bytes) ----
#define WS_LOGPI   0u            // 512 f32
#define WS_VLAST   2048u         // 512 f32
#define WS_BOUND   4096u         // 257 i32
#define WS_ROWMAX  5632u         // 512 f32
#define WS_MAPS    8192u         // 256*512 u16 = 262144
#define WS_LA      270336u       // 512*512 f32 = 1048576 (row-major logA)
#define WS_EMIS    1318912u      // 8192*512 f32 = 16777216
#define WS_BP      18096128u     // 8192*512 u16 = 8388608
#define WS_NEED    26484736u

// Correctly-rounded fp32 logs via fp64 (verified: absmax 0 vs numpy ref).
__global__ void prep_logs(const float* __restrict__ A, const float* __restrict__ Pi,
                          float* __restrict__ lA, float* __restrict__ logPi) {
    int idx = blockIdx.x * blockDim.x + threadIdx.x;
    if (idx < NT * NT) {
        lA[idx] = (float)log((double)A[idx]);
    } else if (idx < NT * NT + NT) {
        int j = idx - NT * NT;
        logPi[j] = (float)log((double)Pi[j]);
    }
}

__global__ void prep_rowmax(const float* __restrict__ lA, float* __restrict__ rowmax) {
    __shared__ float s[4];
    int i = blockIdx.x;
    int t = threadIdx.x;                    // 256 threads
    float m = fmaxf(lA[i * NT + t], lA[i * NT + t + 256]);
    for (int k = 32; k >= 1; k >>= 1) m = fmaxf(m, __shfl_xor(m, k, 64));
    if ((t & 63) == 0) s[t >> 6] = m;
    __syncthreads();
    if (t == 0) {
        float r = fmaxf(fmaxf(s[0], s[1]), fmaxf(s[2], s[3]));
        rowmax[i] = r;
    }
}

__global__ void prep_emis(const float* __restrict__ B, const int* __restrict__ tok,
                          float* __restrict__ emis) {
    int idx = blockIdx.x * blockDim.x + threadIdx.x;   // t*512 + j
    if (idx >= TT * NT) return;
    int t = idx >> 9;
    int j = idx & (NT - 1);
    int tk = tok[t];
    float e;
    if (tk < 0) e = (float)log((double)(1.0f / 512.0f));
    else        e = (float)log((double)B[(size_t)j * MT + tk]);
    emis[idx] = e;
}

// float <-> order-preserving u32 (total order; all values here finite, no NaN)
__device__ __forceinline__ unsigned ordf(float f) {
    unsigned u = __float_as_uint(f);
    return (u & 0x80000000u) ? ~u : (u | 0x80000000u);
}
__device__ __forceinline__ float unordf(unsigned o) {
    return (o & 0x80000000u) ? __uint_as_float(o & 0x7fffffffu)
                             : __uint_as_float(~o);
}

// 512 threads / 8 waves. 4 barriers per step (common path).
__launch_bounds__(NT, 1)
__global__ void viterbi_fwd_exact(const float* __restrict__ lA,
                                  const float* __restrict__ rowmax,
                                  const float* __restrict__ emis,
                                  const float* __restrict__ logPi,
                                  unsigned short* __restrict__ bp,
                                  float* __restrict__ vlast) {
    __shared__ float2 SV[2][560];            // double-buffered survivors (v, idx bits)
    __shared__ float2 SVX[560];              // extras (rare)
    __shared__ alignas(16) float redR[8];    // rowmax partials
    __shared__ alignas(16) float redT[8];    // T partials
    __shared__ int nCtr[2];
    __shared__ int nCtrX;
    __shared__ unsigned long long cmax[NT];  // packed (ord(sc), 511-i) per column

    const int tid  = threadIdx.x;
    const int j    = tid;                    // column AND row owned
    const int lane = tid & 63;
    const int wave = tid >> 6;               // 0..7
    const unsigned long long below = (1ull << lane) - 1ull;
    const float* __restrict__ lAj = lA + j;
    // bank-spread slot for column j: slot=(j&7)<<6 | j>>3 (bijective)
    const int sj = ((j & 7) << 6) | (j >> 3);

    // ---- preamble: warm lA into L1/L2; R; counters; v0; cmax zero ----
    float acc = 0.0f;
    {
        const float4* lAf4 = (const float4*)lA;
        for (int k = tid; k < (NT * NT) / 4; k += NT) acc += lAf4[k].x;
    }
    float r = rowmax[j];
    #pragma unroll
    for (int d = 1; d <= 32; d <<= 1) r = fmaxf(r, __shfl_xor(r, d, 64));
    if (lane == 0) redR[wave] = r;
    if (tid == 0) { nCtr[0] = 0; nCtr[1] = 0; nCtrX = 0; }
    cmax[sj] = 0ull;                         // 0 < ord of any finite float packed
    __syncthreads();
    float4 rr0 = *(const float4*)redR;
    float4 rr1 = *(const float4*)(redR + 4);
    const float R = fmaxf(fmaxf(fmaxf(rr0.x, rr0.y), fmaxf(rr0.z, rr0.w)),
                          fmaxf(fmaxf(rr1.x, rr1.y), fmaxf(rr1.z, rr1.w)));
    if (acc == 1.2345e30f && j == 511) SVX[0].x = acc;   // keep warm loads alive

    float v = logPi[j] + emis[j];            // exact v0 (single-rounded == ref)

    for (int t = 1; t < TT; ++t) {
        const int p = t & 1;
        // ---- PH1: emis issue (nt); per-wave select; compact ----
        float e = __builtin_nontemporal_load(emis + (size_t)t * NT + j);
        float wm = v;
        #pragma unroll
        for (int d = 1; d <= 32; d <<= 1) wm = fmaxf(wm, __shfl_xor(wm, d, 64));
        bool pred = (v >= wm - DELTA_W);
        unsigned long long mk = __ballot(pred);
        int base = 0;
        if (lane == 0) base = atomicAdd(&nCtr[p], __popcll(mk));
        base = __shfl(base, 0, 64);
        if (pred) SV[p][base + __popcll(mk & below)] = make_float2(v, __int_as_float(j));
        __syncthreads();                     // B1: survivors final

        // ---- PH2a: row-parallel scan; wave w handles survivors w, w+8, ... ----
        const int n = nCtr[p];               // >= 8 (each wave's max row selected)
        for (int s = wave; s < n; s += 8) {
            const float2 sv = SV[p][s];      // wave-uniform LDS broadcast
            const int   i  = __float_as_int(sv.y);
            const float vi = sv.x;
            const float* rowp = lA + ((size_t)(unsigned)i << 9) + (lane << 3);
            const float4 c0 = *(const float4*)rowp;        // cols lane*8+0..3
            const float4 c1 = *(const float4*)(rowp + 4);  // cols lane*8+4..7
            const unsigned long long lowb = (unsigned long long)(unsigned)(511 - i);
            float sc0[4] = {c0.x, c0.y, c0.z, c0.w};
            float sc1[4] = {c1.x, c1.y, c1.z, c1.w};
            #pragma unroll
            for (int k = 0; k < 4; ++k) {
                float sc = vi + sc0[k];      // single-rounded add == ref
                atomicMax(&cmax[(k << 6) | lane],
                          ((unsigned long long)ordf(sc) << 32) | lowb);
            }
            #pragma unroll
            for (int k = 0; k < 4; ++k) {
                float sc = vi + sc1[k];
                atomicMax(&cmax[((k + 4) << 6) | lane],
                          ((unsigned long long)ordf(sc) << 32) | lowb);
            }
        }
        __syncthreads();                     // B1.5: all atomics visible

        // ---- PH2b: unpack column max; T partials; resets; re-zero ----
        const unsigned long long key = cmax[sj];
        cmax[sj] = 0ull;                     // safe: next atomics after next B1
        float mval = unordf((unsigned)(key >> 32));
        int   bidx = 511 - (int)(key & 0xffffffffull);
        float tmin = mval;
        #pragma unroll
        for (int d = 1; d <= 32; d <<= 1) tmin = fminf(tmin, __shfl_xor(tmin, d, 64));
        if (lane == 0) redT[wave] = tmin;
        if (tid == 0) { nCtr[p ^ 1] = 0; nCtrX = 0; }
        __syncthreads();                     // B2

        // ---- PH2c: T; extras compact (rare) ----
        float4 t0 = *(const float4*)redT;
        float4 t1 = *(const float4*)(redT + 4);
        float T = fminf(fminf(fminf(t0.x, t0.y), fminf(t0.z, t0.w)),
                        fminf(fminf(t1.x, t1.y), fminf(t1.z, t1.w)));
        bool px = (v + R >= T) && !pred;     // fl(v+R) monotone upper bound
        unsigned long long mkx = __ballot(px);
        if (mkx != 0ull) {                   // ~never
            int bx = 0;
            if (lane == 0) bx = atomicAdd(&nCtrX, __popcll(mkx));
            bx = __shfl(bx, 0, 64);
            if (px) SVX[bx + __popcll(mkx & below)] = make_float2(v, __int_as_float(j));
        }
        __syncthreads();                     // B3

        // ---- PH2d: rare extras scan (serial gather; ~never taken); finalize ----
        const int nX = nCtrX;                // block-uniform
        if (nX > 0) {
            for (int s0 = 0; s0 < nX; s0 += 16) {
                float2 q[16];
                #pragma unroll
                for (int k = 0; k < 16; ++k) {
                    int s = s0 + k;
                    q[k] = SVX[s < nX ? s : nX - 1];
                }
                float a[16];
                #pragma unroll
                for (int k = 0; k < 16; ++k)
                    a[k] = lAj[(size_t)__float_as_int(q[k].y) * NT];
                #pragma unroll
                for (int k = 0; k < 16; ++k) {
                    float sc = q[k].x + a[k];
                    int   is = __float_as_int(q[k].y);
                    if (sc > mval || (sc == mval && is < bidx)) { mval = sc; bidx = is; }
                }
            }
        }
        float vn = mval + e;                 // single-rounded == ref
        __builtin_nontemporal_store((unsigned short)bidx, bp + (size_t)t * NT + j);
        if (t == TT - 1) vlast[j] = vn;
        v = vn;
    }
}

// ---- backtrace: per-segment map composition (verified exact) ----
__launch_bounds__(NT, 1)
__global__ void bt_maps(const unsigned short* __restrict__ bp,
                        unsigned short* __restrict__ maps) {
    __shared__ unsigned short bps[BT_L * NT];
    const int s = blockIdx.x;
    const int tlo = BT_L * s + 1;
    int thi = BT_L * (s + 1); if (thi > TT - 1) thi = TT - 1;
    const int nt = thi - tlo + 1;
    for (int k = threadIdx.x; k < nt * NT; k += NT)
        bps[k] = bp[(size_t)tlo * NT + k];
    __syncthreads();
    int cur = threadIdx.x;
    for (int r = nt - 1; r >= 0; --r) cur = bps[r * NT + cur];
    maps[s * NT + threadIdx.x] = (unsigned short)cur;
}

__launch_bounds__(NT, 1)
__global__ void bt_bound(const float* __restrict__ vlast,
                         const unsigned short* __restrict__ maps,
                         int* __restrict__ bound) {
    __shared__ float sv[NT];
    __shared__ int   si[NT];
    int j = threadIdx.x;
    sv[j] = vlast[j]; si[j] = j;
    __syncthreads();
    for (int off = NT / 2; off > 0; off >>= 1) {
        if (j < off) {
            float v2 = sv[j + off]; int i2 = si[j + off];
            if (v2 > sv[j] || (v2 == sv[j] && i2 < si[j])) { sv[j] = v2; si[j] = i2; }
        }
        __syncthreads();
    }
    if (j == 0) {
        int cur = si[0];
        bound[BT_S] = cur;
        for (int s = BT_S - 1; s >= 0; --s) {
            cur = maps[s * NT + cur];
            bound[s] = cur;
        }
    }
}

__launch_bounds__(NT, 1)
__global__ void bt_path(const unsigned short* __restrict__ bp,
                        const int* __restrict__ bound,
                        int* __restrict__ path) {
    __shared__ unsigned short bps[BT_L * NT];
    const int s = blockIdx.x;
    const int tlo = BT_L * s + 1;
    int thi = BT_L * (s + 1); if (thi > TT - 1) thi = TT - 1;
    const int nt = thi - tlo + 1;
    for (int k = threadIdx.x; k < nt * NT; k += NT)
        bps[k] = bp[(size_t)tlo * NT + k];
    __syncthreads();
    if (threadIdx.x == 0) {
        int cur = bound[s + 1];
        if (s == BT_S - 1) path[TT - 1] = cur;
        for (int r = nt - 1; r >= 0; --r) {
            cur = bps[r * NT + cur];
            path[tlo - 1 + r] = cur;
        }
    }
}

extern "C" void kernel_launch(void* const* d_in, const int* in_sizes, int n_in,
                              void* d_out, int out_size, void* d_ws, size_t ws_size,
                              hipStream_t stream) {
    const int*   tok = (const int*)d_in[0];
    const float* A   = (const float*)d_in[1];
    const float* B   = (const float*)d_in[2];
    const float* Pi  = (const float*)d_in[3];
    int* path = (int*)d_out;
    char* ws = (char*)d_ws;
    if (ws_size < (size_t)WS_NEED) return;

    float* logPi          = (float*)(ws + WS_LOGPI);
    float* vlast          = (float*)(ws + WS_VLAST);
    int*   bound          = (int*)(ws + WS_BOUND);
    float* rowmax         = (float*)(ws + WS_ROWMAX);
    unsigned short* maps  = (unsigned short*)(ws + WS_MAPS);
    float* lA             = (float*)(ws + WS_LA);
    float* emis           = (float*)(ws + WS_EMIS);
    unsigned short* bpp   = (unsigned short*)(ws + WS_BP);

    prep_logs  <<<(NT * NT + NT + 255) / 256, 256, 0, stream>>>(A, Pi, lA, logPi);
    prep_emis  <<<(TT * NT) / 256,            256, 0, stream>>>(B, tok, emis);
    prep_rowmax<<<NT, 256, 0, stream>>>(lA, rowmax);
    viterbi_fwd_exact<<<1, NT, 0, stream>>>(lA, rowmax, emis, logPi, bpp, vlast);
    bt_maps  <<<BT_S, NT, 0, stream>>>(bpp, maps);
    bt_bound <<<1,    NT, 0, stream>>>(vlast, maps, bound);
    bt_path  <<<BT_S, NT, 0, stream>>>(bpp, bound, path);
}